// Round 5
// baseline (202.426 us; speedup 1.0000x reference)
//
#include <hip/hip_runtime.h>

#define EPS 1e-3f

// Tensor geometry (fixed for this problem):
// y1: channel-last bf16 (2, 21,256,256, 16) -- scatter accumulates bf16;
//     conv_l2 consumes it DIRECTLY (bn+relu+f16-convert fused in A-path).
// m1: (2,21,256,256) BYTE mask; slack byte @2752512; 16B ZERO slack line for
//     redirected y1/stage loads @ m1-bytes [2752528, 2752544) (ws byte 90832912)
// m2: (2,11,128,128) fp32;  m3: (2,5,64,64) fp32
// h2h: f16 channel-last (2, 11,128,128, 32) -- 64 B per cell
// h3h: f16 channel-last (2, 5,64,64, 64) -- 128 B per cell
// out: (2,128,64,64) fp32
//
// Lessons encoded:
//  - Implicit-GEMM MFMA wins all conv layers (r17-r20, each verified).
//  - Scatter: packed bf16 atomics + explicit s_waitcnt vmcnt(0) before wave
//    exit (inline-asm atomics invisible to compiler waitcnt; r25, verified).
//  - r24: voxel-driven prezero kills the 88MB y1 memset; byte m1; sc1
//    folded into scatter weights.
//  - r26: h1_pass fused into conv_l2 A-path; masks_pass builds m2+m3.
//  - r27: slack-redirect gave only -4us -> bottleneck is NOT HBM latency but
//    TA TRANSACTIONS: stride-2 16B/lane gathers = ~64 L1 transactions per
//    wave-load; 44 waves/CU x 27 x 64 ~ 76k trans/CU ~ 31us = measured.
//  - r28 (this round): conv_l2 LDS staging. Block = (plane, oy) x 128 px;
//    per kz stage 3 full rows (258 cells, XOR-swizzled vs 16-way bank
//    conflict) via global_load_lds (coalesced 1KB/wave-op, ~8 trans);
//    ds_read_b128 consume; m1 gate bit-packed; oy-major + XCD-chunked
//    block order for halo L2 locality.

// f32 -> bf16 (RNE)
static __device__ __forceinline__ unsigned f2bf(float f) {
    unsigned u = __float_as_uint(f);
    return (u + 0x7FFFu + ((u >> 16) & 1u)) >> 16;
}

typedef _Float16 f16x8 __attribute__((ext_vector_type(8)));
typedef float f32x4 __attribute__((ext_vector_type(4)));
typedef float f32x16 __attribute__((ext_vector_type(16)));

#define SLACK_BYTE 2752512       // m1-relative: guaranteed-zero mask byte
#define SLACK_Y1   90832912      // ws-byte offset of zeroed 16B line

// ---------------- Weight repack + BN fold + memsets + voxel prezero ----------------
// blockIdx < 321: repack.
// 321 <= blockIdx < 1034: memset m1 bytes [0,2752544) + m3, 16B/thread.
// blockIdx >= 1034: one thread per voxel, zero its <=8 y1 cells (32 B each).
// wB2: f16 B-frags 32x32x16 [tap(27)][lane(64)][8]: oc=lane&31; cin=(lane>>5)*8+j
// wB3: f16 B-frags 16x16x32 [tap(27)][tile(4)][lane(64)][8]: oc=tile*16+(lane&15);
//      cin=(lane>>4)*8+j
// wB4: f16 B-frags 16x16x32 [chunk(6)][tile(4)][lane(64)][8]:
//      k=chunk*32+(lane>>4)*8+j; dz=k>>6; cin=k&63; oc=tile*16+(lane&15)
// shb: [0..31]=sh2, [32..95]=sh3, [96..159]=sh4, [160..175]=sc1, [176..191]=sh1
__global__ __launch_bounds__(256) void repack_prezero(
    const float* __restrict__ g1, const float* __restrict__ b1,
    const float* __restrict__ rm1, const float* __restrict__ rv1,
    const float* __restrict__ w2, const float* __restrict__ g2, const float* __restrict__ b2,
    const float* __restrict__ rm2, const float* __restrict__ rv2,
    const float* __restrict__ w3, const float* __restrict__ g3, const float* __restrict__ b3,
    const float* __restrict__ rm3, const float* __restrict__ rv3,
    const float* __restrict__ w4, const float* __restrict__ g4, const float* __restrict__ b4,
    const float* __restrict__ rm4, const float* __restrict__ rv4,
    _Float16* __restrict__ wB2, _Float16* __restrict__ wB3,
    _Float16* __restrict__ wB4, float* __restrict__ shb,
    const int* __restrict__ coors, int NV, unsigned short* __restrict__ y1,
    unsigned char* __restrict__ m1, float* __restrict__ m3)
{
    if (blockIdx.x >= 1034) {
        // ---- prezero: zero the y1 cells this voxel's atomics will touch ----
        const int i = (blockIdx.x - 1034) * 256 + threadIdx.x;
        if (i < NV) {
            const int b = coors[4 * i + 0];
            const int z = coors[4 * i + 1];
            const int y = coors[4 * i + 2];
            const int x = coors[4 * i + 3];
            int ozv[2], nz = 0, oyv[2], ny = 0, oxv[2], nx = 0;
#pragma unroll
            for (int k = 0; k < 3; ++k) {
                int t = z + 1 - k;
                if (t >= 0 && !(t & 1)) { int o = t >> 1; if (o < 21) ozv[nz++] = o; }
            }
#pragma unroll
            for (int k = 0; k < 3; ++k) {
                int t = y + 1 - k;
                if (t >= 0 && !(t & 1)) { int o = t >> 1; if (o < 256) oyv[ny++] = o; }
            }
#pragma unroll
            for (int k = 0; k < 3; ++k) {
                int t = x + 1 - k;
                if (t >= 0 && !(t & 1)) { int o = t >> 1; if (o < 256) oxv[nx++] = o; }
            }
            const uint4 zz = {0u, 0u, 0u, 0u};
            for (int a = 0; a < nz; ++a)
                for (int bb = 0; bb < ny; ++bb)
                    for (int c = 0; c < nx; ++c) {
                        const int sp = ozv[a] * 65536 + oyv[bb] * 256 + oxv[c];
                        uint4* p = (uint4*)(y1 + (size_t)(b * 1376256 + sp) * 16);
                        p[0] = zz;
                        p[1] = zz;
                    }
        }
        asm volatile("s_waitcnt vmcnt(0)" ::: "memory");
        return;
    }
    if (blockIdx.x >= 321) {
        // ---- memset role: m1 bytes [0, 2752544) + m3 floats [0, 40960) ----
        const int idx16 = (blockIdx.x - 321) * 256 + threadIdx.x;
        const uint4 zz = {0u, 0u, 0u, 0u};
        if (idx16 < 172034) {
            ((uint4*)m1)[idx16] = zz;    // covers slack byte AND zero y1-slack line
        } else if (idx16 < 182274) {
            ((uint4*)m3)[idx16 - 172034] = zz;
        }
        return;
    }

    const int i = blockIdx.x * 256 + threadIdx.x;
    if (i < 13824) {                       // wB2[tap*512 + lane*8 + j]
        const int j = i & 7, lane = (i >> 3) & 63, tap = i >> 9;
        const int oc = lane & 31;
        const int cin = (lane >> 5) * 8 + j;
        const float inv = g2[oc] * rsqrtf(rv2[oc] + EPS);
        wB2[i] = (_Float16)(w2[(oc * 16 + cin) * 27 + tap] * inv);
    } else if (i >= 14336 && i < 69632) {  // wB3
        const int j2 = i - 14336;
        const int j = j2 & 7, lane = (j2 >> 3) & 63, t = (j2 >> 9) & 3, tap = j2 >> 11;
        const int q = lane >> 4, n = lane & 15;
        const int oc = t * 16 + n;
        const int cin = q * 8 + j;
        const float inv = g3[oc] * rsqrtf(rv3[oc] + EPS);
        wB3[j2] = (_Float16)(w3[(oc * 32 + cin) * 27 + tap] * inv);
    } else if (i >= 69632 && i < 81920) {  // wB4
        const int j2 = i - 69632;
        const int j = j2 & 7, lane = (j2 >> 3) & 63, t = (j2 >> 9) & 3, c = j2 >> 11;
        const int q = lane >> 4, n = lane & 15;
        const int oc = t * 16 + n;
        const int k = c * 32 + q * 8 + j;
        const int dz = k >> 6, cin = k & 63;
        const float inv = g4[oc] * rsqrtf(rv4[oc] + EPS);
        wB4[j2] = (_Float16)(w4[(oc * 64 + cin) * 3 + dz] * inv);
    } else if (i >= 81920 && i < 82112) {  // shifts + L1 BN scale/shift
        const int j = i - 81920;
        if (j < 32) {
            const float inv = g2[j] * rsqrtf(rv2[j] + EPS);
            shb[j] = b2[j] - rm2[j] * inv;
        } else if (j < 96) {
            const int o = j - 32;
            const float inv = g3[o] * rsqrtf(rv3[o] + EPS);
            shb[j] = b3[o] - rm3[o] * inv;
        } else if (j < 160) {
            const int o = j - 96;
            const float inv = g4[o] * rsqrtf(rv4[o] + EPS);
            shb[j] = b4[o] - rm4[o] * inv;
        } else if (j < 176) {
            const int o = j - 160;
            shb[j] = g1[o] * rsqrtf(rv1[o] + EPS);           // sc1
        } else if (j < 192) {
            const int o = j - 176;
            const float inv = g1[o] * rsqrtf(rv1[o] + EPS);
            shb[j] = b1[o] - rm1[o] * inv;                   // sh1
        }
    }
}

// ---------------- Layer 1: voxel scatter, one thread per (voxel, oc-pair) ----------------
__global__ __launch_bounds__(256) void scatter_l1(
    const float* __restrict__ vf, const int* __restrict__ coors, int NV,
    const float* __restrict__ w1, const float* __restrict__ shb,
    unsigned short* __restrict__ y1, unsigned char* __restrict__ m1)
{
    __shared__ float ws[16 * 3 * 27];  // (oc, c, tap) -- pre-scaled by sc1[oc]
    for (int e = threadIdx.x; e < 16 * 3 * 27; e += 256)
        ws[e] = w1[e] * shb[160 + e / 81];
    __syncthreads();

    const int gid = blockIdx.x * 256 + threadIdx.x;
    const int i = gid >> 3;        // voxel
    const int oc2 = gid & 7;       // channel pair
    if (i < NV) {
        const int oc = oc2 * 2;

        const int b = coors[4 * i + 0];
        const int z = coors[4 * i + 1];
        const int y = coors[4 * i + 2];
        const int x = coors[4 * i + 3];
        const float f0 = vf[3 * i + 0];
        const float f1 = vf[3 * i + 1];
        const float f2 = vf[3 * i + 2];

        int ozv[2], kzv[2], nz = 0;
        int oyv[2], kyv[2], ny = 0;
        int oxv[2], kxv[2], nx = 0;
#pragma unroll
        for (int k = 0; k < 3; ++k) {
            int t = z + 1 - k;
            if (t >= 0 && !(t & 1)) { int o = t >> 1; if (o < 21) { ozv[nz] = o; kzv[nz] = k; ++nz; } }
        }
#pragma unroll
        for (int k = 0; k < 3; ++k) {
            int t = y + 1 - k;
            if (t >= 0 && !(t & 1)) { int o = t >> 1; if (o < 256) { oyv[ny] = o; kyv[ny] = k; ++ny; } }
        }
#pragma unroll
        for (int k = 0; k < 3; ++k) {
            int t = x + 1 - k;
            if (t >= 0 && !(t & 1)) { int o = t >> 1; if (o < 256) { oxv[nx] = o; kxv[nx] = k; ++nx; } }
        }

        for (int a = 0; a < nz; ++a)
            for (int bb = 0; bb < ny; ++bb)
                for (int c = 0; c < nx; ++c) {
                    const int oz = ozv[a], oy = oyv[bb], ox = oxv[c];
                    const int tap = (kzv[a] * 3 + kyv[bb]) * 3 + kxv[c];
                    const int sp = oz * 65536 + oy * 256 + ox;
                    if (oc2 == 0) m1[b * 1376256 + sp] = 1;
                    const float s0 = ws[oc * 81 + tap] * f0 + ws[oc * 81 + 27 + tap] * f1 +
                                     ws[oc * 81 + 54 + tap] * f2;
                    const float s1 = ws[(oc + 1) * 81 + tap] * f0 +
                                     ws[(oc + 1) * 81 + 27 + tap] * f1 +
                                     ws[(oc + 1) * 81 + 54 + tap] * f2;
                    const unsigned pk = f2bf(s0) | (f2bf(s1) << 16);
                    unsigned* addr = (unsigned*)(y1 + (size_t)(b * 1376256 + sp) * 16 +
                                                 oc2 * 2);
                    asm volatile("global_atomic_pk_add_bf16 %0, %1, off"
                                 : : "v"(addr), "v"(pk) : "memory");
                }
    }
    // CRITICAL (r25): drain inline-asm atomics before the wave can end.
    asm volatile("s_waitcnt vmcnt(0)" ::: "memory");
}

// ---------------- masks: m2 from m1 (27-OR); m3 via scatter-stores ----------------
__global__ __launch_bounds__(256) void masks_pass(
    const unsigned char* __restrict__ m1, float* __restrict__ m2,
    float* __restrict__ m3)
{
    const int idx = blockIdx.x * 256 + threadIdx.x;   // < 360448
    const int b = idx / 180224;
    const int r = idx - b * 180224;
    const int oz = r >> 14, r2 = r & 16383, oy = r2 >> 7, ox = r2 & 127;
    const int iz0 = 2 * oz - 1, iyb = 2 * oy - 1, ixb = 2 * ox - 1;
    unsigned msum = 0;
#pragma unroll
    for (int kz = 0; kz < 3; ++kz) {
        const int iz = iz0 + kz;
#pragma unroll
        for (int ky = 0; ky < 3; ++ky) {
            const int iy = iyb + ky;
#pragma unroll
            for (int kx = 0; kx < 3; ++kx) {
                const int ix = ixb + kx;
                if ((unsigned)iz < 21u && (unsigned)iy < 256u &&
                    (unsigned)ix < 256u)
                    msum |= m1[b * 1376256 + iz * 65536 + iy * 256 + ix];
            }
        }
    }
    m2[idx] = msum ? 1.f : 0.f;

    if (msum) {
        // parent m3 windows of this m2 px: z pad0 (o=(oz-k)/2), y/x pad1
        int ozv[2], nz = 0, oyv[2], ny = 0, oxv[2], nx = 0;
#pragma unroll
        for (int k = 0; k < 3; ++k) {
            int t = oz - k;
            if (t >= 0 && !(t & 1)) { int o = t >> 1; if (o < 5) ozv[nz++] = o; }
        }
#pragma unroll
        for (int k = 0; k < 3; ++k) {
            int t = oy + 1 - k;
            if (t >= 0 && !(t & 1)) { int o = t >> 1; if (o < 64) oyv[ny++] = o; }
        }
#pragma unroll
        for (int k = 0; k < 3; ++k) {
            int t = ox + 1 - k;
            if (t >= 0 && !(t & 1)) { int o = t >> 1; if (o < 64) oxv[nx++] = o; }
        }
        for (int a = 0; a < nz; ++a)
            for (int bb = 0; bb < ny; ++bb)
                for (int c = 0; c < nx; ++c)
                    m3[b * 20480 + ozv[a] * 4096 + oyv[bb] * 64 + oxv[c]] = 1.0f;
    }
}

// ---------------- Layer 2: LDS-staged implicit-GEMM MFMA 32x32x16 conv 16->32 ----------------
// Block = (plane, oy) x 128 output px; 4 waves each own a 32-px strip.
// Per kz: stage 3 full input rows (258 cells x 32B, XOR-swizzled) into LDS via
// global_load_lds (coalesced), then 9 taps of ds_read_b128 + fused bn/relu/f16
// + MFMA. Inactive cells gated by bit-packed m1 mask (staged poison zeroed).
// Row pitch 8320B (128B-aligned for swizzle); OOB rows/cells stage from slack.
__global__ __launch_bounds__(256) __attribute__((amdgpu_waves_per_eu(4, 8)))
void conv_l2(
    const unsigned char* __restrict__ y1c,  // ws base, byte-addressed
    const unsigned char* __restrict__ m1,
    const uint4* __restrict__ wB2,
    const float* __restrict__ m2, const float* __restrict__ shb,
    _Float16* __restrict__ h2h)
{
    __shared__ unsigned char lds[3 * 8320];   // 3 rows x 520 16B-units

    const int tid = threadIdx.x;
    const int lane = tid & 63;
    const int w = tid >> 6;
    const int m = lane & 31, h = lane >> 5;

    // oy-major order + XCD-chunked swizzle (2816 = 8 x 352, bijective):
    // each XCD gets contiguous blocks -> y/z halo reuse stays in its L2.
    const int sbid = (blockIdx.x & 7) * 352 + (blockIdx.x >> 3);
    const int oy = sbid / 22;
    const int plane = sbid - oy * 22;          // b*11 + oz
    const int b = plane / 11, oz = plane - b * 11;

    const int ox0 = w * 32;
    const int iz0 = 2 * oz - 1, iyb = 2 * oy - 1;
    const int ixm = 2 * (ox0 + m) - 1;
    const int bbase = b * 1376256;
    const int qoff = h * 16;

    // ---- mask prefetch -> bit-pack (27 bits) ----
    unsigned mbits = 0;
#pragma unroll
    for (int t = 0; t < 27; ++t) {
        const int kz = t / 9, ky = (t / 3) % 3, kx = t % 3;
        const int iz = iz0 + kz, iy = iyb + ky, ix = ixm + kx;
        const bool v = (unsigned)iz < 21u && (unsigned)iy < 256u &&
                       (unsigned)ix < 256u;
        const int cell = bbase + iz * 65536 + iy * 256 + ix;
        mbits |= (unsigned)(m1[v ? cell : SLACK_BYTE] & 1) << t;
    }

    // per-lane bn shifts for channels h*8 .. h*8+7
    float s1v[8];
    {
        const float4* sp = (const float4*)(shb + 176 + h * 8);
        const float4 a0 = sp[0], a1 = sp[1];
        s1v[0] = a0.x; s1v[1] = a0.y; s1v[2] = a0.z; s1v[3] = a0.w;
        s1v[4] = a1.x; s1v[5] = a1.y; s1v[6] = a1.z; s1v[7] = a1.w;
    }

    // ---- reader LDS byte offsets per kx (swizzled) ----
    int rdo[3];
#pragma unroll
    for (int kx = 0; kx < 3; ++kx) {
        const unsigned lx = (unsigned)(2 * (ox0 + m) + kx);   // 0..256
        const unsigned L = lx * 32 + qoff;
        rdo[kx] = (int)(L ^ (((L >> 7) & 7u) << 4));
    }

    // ---- stage-unit geometry (kz-independent): physical unit -> source cell ----
    // physical unit p in row: logical L = (p*16) ^ (((p>>3)&7)<<4);
    // lx = L>>5, half = (L>>4)&1, ix = lx-1  (involution with reader swizzle)
    int su_row[7], su_ix[7], su_half[7];
#pragma unroll
    for (int it = 0; it < 7; ++it) {
        const int t = it * 256 + tid;                 // < 1792
        const int row = t / 520;                      // 0..3 (3 = inactive)
        const int u = t - row * 520;
        const unsigned L = (unsigned)(u * 16) ^ (((unsigned)(u >> 3) & 7u) << 4);
        su_row[it] = row;
        su_ix[it] = (int)(L >> 5) - 1;
        su_half[it] = (int)((L >> 4) & 1u);
    }

    f32x16 acc;
#pragma unroll
    for (int r = 0; r < 16; ++r) acc[r] = 0.f;

    for (int kz = 0; kz < 3; ++kz) {
        const int iz = iz0 + kz;
        const bool izok = (unsigned)iz < 21u;
        const int zrow = bbase + iz * 65536;

        __syncthreads();    // prior consume done before LDS overwrite
#pragma unroll
        for (int it = 0; it < 7; ++it) {
            const int t = it * 256 + tid;
            if (t < 1560) {
                const int row = su_row[it];
                const int iy = iyb + row;
                const int ix = su_ix[it];
                const bool v = izok && (unsigned)iy < 256u && (unsigned)ix < 256u;
                const int srcb = v ? ((zrow + iy * 256 + ix) * 32 + su_half[it] * 16)
                                   : (int)SLACK_Y1;
                const int bt = t - lane;              // wave-uniform LDS base
                __builtin_amdgcn_global_load_lds(
                    (const __attribute__((address_space(1))) unsigned char*)(y1c + srcb),
                    (__attribute__((address_space(3))) unsigned char*)(lds + bt * 16),
                    16, 0, 0);
            }
        }
        asm volatile("s_waitcnt vmcnt(0)" ::: "memory");
        __syncthreads();

#pragma unroll
        for (int ky = 0; ky < 3; ++ky) {
            const int rbase = ky * 8320;
#pragma unroll
            for (int kx = 0; kx < 3; ++kx) {
                const int tap = kz * 9 + ky * 3 + kx;
                const uint4 ua = *(const uint4*)(lds + rbase + rdo[kx]);
                const bool act = (mbits >> tap) & 1u;
                unsigned od[4];
                const unsigned dvs[4] = {ua.x, ua.y, ua.z, ua.w};
#pragma unroll
                for (int jj = 0; jj < 4; ++jj) {
                    const unsigned dv = dvs[jj];
                    const float vlo = fmaxf(__uint_as_float(dv << 16) + s1v[2 * jj], 0.f);
                    const float vhi = fmaxf(__uint_as_float(dv & 0xFFFF0000u) + s1v[2 * jj + 1], 0.f);
                    const unsigned pk = __builtin_bit_cast(
                        unsigned, __builtin_amdgcn_cvt_pkrtz(vlo, vhi));
                    od[jj] = act ? pk : 0u;
                }
                const uint4 uc = {od[0], od[1], od[2], od[3]};
                const f16x8 af = __builtin_bit_cast(f16x8, uc);
                const f16x8 bf = __builtin_bit_cast(f16x8, wB2[tap * 64 + lane]);
                acc = __builtin_amdgcn_mfma_f32_32x32x16_f16(af, bf, acc, 0, 0, 0);
            }
        }
    }

    // epilogue: col=lane&31 (oc), row=(r&3)+8*(r>>2)+4*(lane>>5) (px)
    const int oc = lane & 31;
#pragma unroll
    for (int r = 0; r < 16; ++r) {
        const int row = (r & 3) + 8 * (r >> 2) + 4 * h;
        const int px = ox0 + row;
        const int spo = oz * 16384 + oy * 128 + px;
        const float mv = m2[b * 180224 + spo];
        const size_t cbase = (size_t)(b * 180224 + spo) * 32;
        h2h[cbase + oc] = (_Float16)(fmaxf(acc[r] + shb[oc], 0.f) * mv);
    }
}

// ---------------- Layer 3: implicit-GEMM MFMA conv 32->64 ----------------
__global__ __launch_bounds__(256) __attribute__((amdgpu_waves_per_eu(4, 8)))
void conv_l3(
    const unsigned char* __restrict__ h2h,  // f16 cells, byte-addressed
    const uint4* __restrict__ wB3,
    const float* __restrict__ m3, const float* __restrict__ shb,
    _Float16* __restrict__ h3h)
{
    const int tid = threadIdx.x;
    const int gw = blockIdx.x * 4 + (tid >> 6);     // 0..2559
    const int lane = tid & 63;
    const int m = lane & 15, q = lane >> 4;

    const int plane = gw >> 8;                      // b*5+oz
    const int rem = gw & 255;
    const int oy = rem >> 2;
    const int ox0 = (rem & 3) * 16;
    const int b = plane / 5, oz = plane % 5;
    const int iz0 = 2 * oz, iyb = 2 * oy - 1;       // z pad 0
    const int ixm = 2 * (ox0 + m) - 1;
    const int bbase = b * 180224;
    const int qoff = q * 16;                        // byte offset in 64B cell

    f32x4 acc[4];
#pragma unroll
    for (int t = 0; t < 4; ++t) acc[t] = (f32x4){0.f, 0.f, 0.f, 0.f};

    uint4 buf[9];
    bool  val[9];
#pragma unroll
    for (int t = 0; t < 9; ++t) {
        const int ky = (t / 3) % 3, kx = t % 3;
        const int iz = iz0 + t / 9, iy = iyb + ky, ix = ixm + kx;
        const bool v = (unsigned)iy < 128u && (unsigned)ix < 128u;
        const int cell = bbase + iz * 16384 + iy * 128 + ix;
        buf[t] = *(const uint4*)(h2h + (v ? (cell * 64 + qoff) : 0));
        val[t] = v;
    }

#pragma unroll
    for (int tap = 0; tap < 27; ++tap) {
        const int s = tap % 9;
        uint4 ua = buf[s];
        if (!val[s]) { ua.x = 0; ua.y = 0; ua.z = 0; ua.w = 0; }
        if (tap + 9 < 27) {
            const int t2 = tap + 9;
            const int kz = t2 / 9, ky = (t2 / 3) % 3, kx = t2 % 3;
            const int iz = iz0 + kz, iy = iyb + ky, ix = ixm + kx;
            const bool v = (unsigned)iy < 128u && (unsigned)ix < 128u;
            const int cell = bbase + iz * 16384 + iy * 128 + ix;
            buf[s] = *(const uint4*)(h2h + (v ? (cell * 64 + qoff) : 0));
            val[s] = v;
        }
        const f16x8 af = __builtin_bit_cast(f16x8, ua);
#pragma unroll
        for (int t = 0; t < 4; ++t) {
            const f16x8 bf = __builtin_bit_cast(f16x8, wB3[(tap * 4 + t) * 64 + lane]);
            acc[t] = __builtin_amdgcn_mfma_f32_16x16x32_f16(af, bf, acc[t], 0, 0, 0);
        }
    }

    const int n = lane & 15;
#pragma unroll
    for (int r = 0; r < 4; ++r) {
        const int px = ox0 + q * 4 + r;
        const int spo = oz * 4096 + oy * 64 + px;
        const float mv = m3[b * 20480 + spo];
        const size_t cb = (size_t)(b * 20480 + spo) * 64;
#pragma unroll
        for (int t = 0; t < 4; ++t) {
            const int oc = t * 16 + n;
            h3h[cb + oc] = (_Float16)(fmaxf(acc[t][r] + shb[32 + oc], 0.f) * mv);
        }
    }
}

// ---------------- Layer 4: implicit-GEMM MFMA conv 64->64, k(3,1,1) ----------------
__global__ __launch_bounds__(256) __attribute__((amdgpu_waves_per_eu(4, 8)))
void conv_l4(
    const unsigned char* __restrict__ h3h,  // f16 cells (128 B), byte-addressed
    const uint4* __restrict__ wB4,
    const float* __restrict__ m3, const float* __restrict__ shb,
    float* __restrict__ out)
{
    const int tid = threadIdx.x;
    const int gw = blockIdx.x * 4 + (tid >> 6);     // 0..1023
    const int lane = tid & 63;
    const int m = lane & 15, q = lane >> 4;

    const int b = gw >> 9, od = (gw >> 8) & 1;
    const int oy = (gw >> 2) & 63, ox0 = (gw & 3) * 16;
    const int cellbase = (b * 5 + 2 * od) * 4096 + oy * 64 + ox0 + m;

    f32x4 acc[4];
#pragma unroll
    for (int t = 0; t < 4; ++t) acc[t] = (f32x4){0.f, 0.f, 0.f, 0.f};

#pragma unroll
    for (int c = 0; c < 6; ++c) {
        const int dz = c >> 1;
        const size_t addr = (size_t)(cellbase + dz * 4096) * 128 +
                            (c & 1) * 64 + q * 16;
        const uint4 ua = *(const uint4*)(h3h + addr);
        const f16x8 af = __builtin_bit_cast(f16x8, ua);
#pragma unroll
        for (int t = 0; t < 4; ++t) {
            const f16x8 bf = __builtin_bit_cast(f16x8, wB4[(c * 4 + t) * 64 + lane]);
            acc[t] = __builtin_amdgcn_mfma_f32_16x16x32_f16(af, bf, acc[t], 0, 0, 0);
        }
    }

    const int n = lane & 15;
#pragma unroll
    for (int r = 0; r < 4; ++r) {
        const int px = ox0 + q * 4 + r;
        const int spo = oy * 64 + px;
        const float msum = m3[(b * 5 + 2 * od + 0) * 4096 + spo] +
                           m3[(b * 5 + 2 * od + 1) * 4096 + spo] +
                           m3[(b * 5 + 2 * od + 2) * 4096 + spo];
        const float mv = msum > 0.f ? 1.f : 0.f;
#pragma unroll
        for (int t = 0; t < 4; ++t) {
            const int oc = t * 16 + n;
            out[((b * 64 + oc) * 2 + od) * 4096 + spo] =
                fmaxf(acc[t][r] + shb[96 + oc], 0.f) * mv;
        }
    }
}

extern "C" void kernel_launch(void* const* d_in, const int* in_sizes, int n_in,
                              void* d_out, int out_size, void* d_ws, size_t ws_size,
                              hipStream_t stream)
{
    const float* vf    = (const float*)d_in[0];
    const int*   coors = (const int*)d_in[1];
    // d_in[2] = batch_size (==2, hardcoded in geometry)
    const float* w1 = (const float*)d_in[3];
    const float* g1 = (const float*)d_in[4];
    const float* b1 = (const float*)d_in[5];
    const float* rm1 = (const float*)d_in[6];
    const float* rv1 = (const float*)d_in[7];
    const float* w2 = (const float*)d_in[8];
    const float* g2 = (const float*)d_in[9];
    const float* b2 = (const float*)d_in[10];
    const float* rm2 = (const float*)d_in[11];
    const float* rv2 = (const float*)d_in[12];
    const float* w3 = (const float*)d_in[13];
    const float* g3 = (const float*)d_in[14];
    const float* b3 = (const float*)d_in[15];
    const float* rm3 = (const float*)d_in[16];
    const float* rv3 = (const float*)d_in[17];
    const float* w4 = (const float*)d_in[18];
    const float* g4 = (const float*)d_in[19];
    const float* b4 = (const float*)d_in[20];
    const float* rm4 = (const float*)d_in[21];
    const float* rv4 = (const float*)d_in[22];

    const int NV = in_sizes[0] / 3;

    float* ws = (float*)d_ws;
    float* y1  = ws;                   // 22,020,096 f-slots: bf16 (2,21,256,256,16)
    float* m1f = y1 + 22020096;        //  2,752,544 BYTES used (mask+slack+zero line)
    float* h2h = m1f + 2752512;        //  5,767,168 f-slots: f16 (2,11,128,128,32)
    float* m2  = h2h + 5767168;        //    360,448 f  (2,11,128,128)
    float* h3h = m2 + 360448;          //  1,310,720 f-slots: f16 (2,5,64,64,64)
    float* m3  = h3h + 1310720;        //     40,960 f  (2,5,64,64)
    float* wB2 = m3 + 40960;           //      7,168 f-slots (13824 f16 used)
    float* wB3 = wB2 + 7168;           //     27,648 f-slots (55296 f16)
    float* wB4 = wB3 + 27648;          //      6,144 f-slots (12288 f16)
    float* shb = wB4 + 6144;           //        192 f

    unsigned char* m1 = (unsigned char*)m1f;

    const int pzBlocks = (NV + 255) / 256;
    repack_prezero<<<1034 + pzBlocks, 256, 0, stream>>>(
        g1, b1, rm1, rv1,
        w2, g2, b2, rm2, rv2, w3, g3, b3, rm3, rv3,
        w4, g4, b4, rm4, rv4,
        (_Float16*)wB2, (_Float16*)wB3, (_Float16*)wB4, shb,
        coors, NV, (unsigned short*)y1, m1, m3);
    scatter_l1<<<(NV * 8 + 255) / 256, 256, 0, stream>>>(vf, coors, NV, w1, shb,
                                                         (unsigned short*)y1, m1);
    masks_pass<<<1408, 256, 0, stream>>>(m1, m2, m3);
    conv_l2<<<2816, 256, 0, stream>>>((const unsigned char*)d_ws, m1,
                                      (const uint4*)wB2, m2, shb, (_Float16*)h2h);
    conv_l3<<<640, 256, 0, stream>>>((const unsigned char*)h2h, (const uint4*)wB3,
                                     m3, shb, (_Float16*)h3h);
    conv_l4<<<256, 256, 0, stream>>>((const unsigned char*)h3h, (const uint4*)wB4,
                                     m3, shb, (float*)d_out);
}

// Round 6
// 195.744 us; speedup vs baseline: 1.0341x; 1.0341x over previous
//
#include <hip/hip_runtime.h>

#define EPS 1e-3f

// Tensor geometry (fixed for this problem):
// y1: channel-last bf16 (2, 21,256,256, 16) -- scatter accumulates bf16;
//     conv_l2 consumes it DIRECTLY (bn+relu+f16-convert fused at STAGE time).
// m1: (2,21,256,256) BYTE mask; slack byte @2752512; 16B ZERO slack line for
//     redirected y1/stage loads @ m1-bytes [2752528, 2752544) (ws byte 90832912)
// m2: (2,11,128,128) fp32;  m3: (2,5,64,64) fp32
// h2h: f16 channel-last (2, 11,128,128, 32) -- 64 B per cell
// h3h: f16 channel-last (2, 5,64,64, 64) -- 128 B per cell
// out: (2,128,64,64) fp32
//
// Lessons encoded:
//  - Implicit-GEMM MFMA wins all conv layers (r17-r20, each verified).
//  - Scatter: packed bf16 atomics + explicit s_waitcnt vmcnt(0) before wave
//    exit (inline-asm atomics invisible to compiler waitcnt; r25, verified).
//  - r24: voxel-driven prezero kills the 88MB y1 memset; byte m1; sc1
//    folded into scatter weights.
//  - r26: h1_pass fused into conv_l2; masks_pass builds m2+m3.
//  - r27: slack-redirect -4us only -> not HBM-latency-bound.
//  - r28: LDS staging: FETCH 83->55MB, conflicts 1.2M, but dur flat 45us and
//    VALUBusy 42->62% -> conv_l2 is VALU-bound: per-tap conversion (675 ops)
//    + mbits gather (220 ops) in the consume path, conversion re-done 3x per
//    cell (kx reuse).
//  - r29 (this round): conversion+gate moved to STAGE time via reg-staging
//    (global->reg->convert->ds_write_b128). Inner loop = ds_read + MFMA only.
//    Both sides apply the same logical->physical XOR swizzle (rule #21:
//    reg-staging frees the layout). Stage order chosen so each thread's
//    units share one cell-half (520 even => u&1 = tid&1) -> 8 shift regs.
//    mbits gather deleted.

// f32 -> bf16 (RNE)
static __device__ __forceinline__ unsigned f2bf(float f) {
    unsigned u = __float_as_uint(f);
    return (u + 0x7FFFu + ((u >> 16) & 1u)) >> 16;
}

typedef _Float16 f16x8 __attribute__((ext_vector_type(8)));
typedef float f32x4 __attribute__((ext_vector_type(4)));
typedef float f32x16 __attribute__((ext_vector_type(16)));

#define SLACK_BYTE 2752512       // m1-relative: guaranteed-zero mask byte
#define SLACK_Y1   90832912      // ws-byte offset of zeroed 16B line

// ---------------- Weight repack + BN fold + memsets + voxel prezero ----------------
// blockIdx < 321: repack.
// 321 <= blockIdx < 1034: memset m1 bytes [0,2752544) + m3, 16B/thread.
// blockIdx >= 1034: one thread per voxel, zero its <=8 y1 cells (32 B each).
// wB2: f16 B-frags 32x32x16 [tap(27)][lane(64)][8]: oc=lane&31; cin=(lane>>5)*8+j
// wB3: f16 B-frags 16x16x32 [tap(27)][tile(4)][lane(64)][8]: oc=tile*16+(lane&15);
//      cin=(lane>>4)*8+j
// wB4: f16 B-frags 16x16x32 [chunk(6)][tile(4)][lane(64)][8]:
//      k=chunk*32+(lane>>4)*8+j; dz=k>>6; cin=k&63; oc=tile*16+(lane&15)
// shb: [0..31]=sh2, [32..95]=sh3, [96..159]=sh4, [160..175]=sc1, [176..191]=sh1
__global__ __launch_bounds__(256) void repack_prezero(
    const float* __restrict__ g1, const float* __restrict__ b1,
    const float* __restrict__ rm1, const float* __restrict__ rv1,
    const float* __restrict__ w2, const float* __restrict__ g2, const float* __restrict__ b2,
    const float* __restrict__ rm2, const float* __restrict__ rv2,
    const float* __restrict__ w3, const float* __restrict__ g3, const float* __restrict__ b3,
    const float* __restrict__ rm3, const float* __restrict__ rv3,
    const float* __restrict__ w4, const float* __restrict__ g4, const float* __restrict__ b4,
    const float* __restrict__ rm4, const float* __restrict__ rv4,
    _Float16* __restrict__ wB2, _Float16* __restrict__ wB3,
    _Float16* __restrict__ wB4, float* __restrict__ shb,
    const int* __restrict__ coors, int NV, unsigned short* __restrict__ y1,
    unsigned char* __restrict__ m1, float* __restrict__ m3)
{
    if (blockIdx.x >= 1034) {
        // ---- prezero: zero the y1 cells this voxel's atomics will touch ----
        const int i = (blockIdx.x - 1034) * 256 + threadIdx.x;
        if (i < NV) {
            const int b = coors[4 * i + 0];
            const int z = coors[4 * i + 1];
            const int y = coors[4 * i + 2];
            const int x = coors[4 * i + 3];
            int ozv[2], nz = 0, oyv[2], ny = 0, oxv[2], nx = 0;
#pragma unroll
            for (int k = 0; k < 3; ++k) {
                int t = z + 1 - k;
                if (t >= 0 && !(t & 1)) { int o = t >> 1; if (o < 21) ozv[nz++] = o; }
            }
#pragma unroll
            for (int k = 0; k < 3; ++k) {
                int t = y + 1 - k;
                if (t >= 0 && !(t & 1)) { int o = t >> 1; if (o < 256) oyv[ny++] = o; }
            }
#pragma unroll
            for (int k = 0; k < 3; ++k) {
                int t = x + 1 - k;
                if (t >= 0 && !(t & 1)) { int o = t >> 1; if (o < 256) oxv[nx++] = o; }
            }
            const uint4 zz = {0u, 0u, 0u, 0u};
            for (int a = 0; a < nz; ++a)
                for (int bb = 0; bb < ny; ++bb)
                    for (int c = 0; c < nx; ++c) {
                        const int sp = ozv[a] * 65536 + oyv[bb] * 256 + oxv[c];
                        uint4* p = (uint4*)(y1 + (size_t)(b * 1376256 + sp) * 16);
                        p[0] = zz;
                        p[1] = zz;
                    }
        }
        asm volatile("s_waitcnt vmcnt(0)" ::: "memory");
        return;
    }
    if (blockIdx.x >= 321) {
        // ---- memset role: m1 bytes [0, 2752544) + m3 floats [0, 40960) ----
        const int idx16 = (blockIdx.x - 321) * 256 + threadIdx.x;
        const uint4 zz = {0u, 0u, 0u, 0u};
        if (idx16 < 172034) {
            ((uint4*)m1)[idx16] = zz;    // covers slack byte AND zero y1-slack line
        } else if (idx16 < 182274) {
            ((uint4*)m3)[idx16 - 172034] = zz;
        }
        return;
    }

    const int i = blockIdx.x * 256 + threadIdx.x;
    if (i < 13824) {                       // wB2[tap*512 + lane*8 + j]
        const int j = i & 7, lane = (i >> 3) & 63, tap = i >> 9;
        const int oc = lane & 31;
        const int cin = (lane >> 5) * 8 + j;
        const float inv = g2[oc] * rsqrtf(rv2[oc] + EPS);
        wB2[i] = (_Float16)(w2[(oc * 16 + cin) * 27 + tap] * inv);
    } else if (i >= 14336 && i < 69632) {  // wB3
        const int j2 = i - 14336;
        const int j = j2 & 7, lane = (j2 >> 3) & 63, t = (j2 >> 9) & 3, tap = j2 >> 11;
        const int q = lane >> 4, n = lane & 15;
        const int oc = t * 16 + n;
        const int cin = q * 8 + j;
        const float inv = g3[oc] * rsqrtf(rv3[oc] + EPS);
        wB3[j2] = (_Float16)(w3[(oc * 32 + cin) * 27 + tap] * inv);
    } else if (i >= 69632 && i < 81920) {  // wB4
        const int j2 = i - 69632;
        const int j = j2 & 7, lane = (j2 >> 3) & 63, t = (j2 >> 9) & 3, c = j2 >> 11;
        const int q = lane >> 4, n = lane & 15;
        const int oc = t * 16 + n;
        const int k = c * 32 + q * 8 + j;
        const int dz = k >> 6, cin = k & 63;
        const float inv = g4[oc] * rsqrtf(rv4[oc] + EPS);
        wB4[j2] = (_Float16)(w4[(oc * 64 + cin) * 3 + dz] * inv);
    } else if (i >= 81920 && i < 82112) {  // shifts + L1 BN scale/shift
        const int j = i - 81920;
        if (j < 32) {
            const float inv = g2[j] * rsqrtf(rv2[j] + EPS);
            shb[j] = b2[j] - rm2[j] * inv;
        } else if (j < 96) {
            const int o = j - 32;
            const float inv = g3[o] * rsqrtf(rv3[o] + EPS);
            shb[j] = b3[o] - rm3[o] * inv;
        } else if (j < 160) {
            const int o = j - 96;
            const float inv = g4[o] * rsqrtf(rv4[o] + EPS);
            shb[j] = b4[o] - rm4[o] * inv;
        } else if (j < 176) {
            const int o = j - 160;
            shb[j] = g1[o] * rsqrtf(rv1[o] + EPS);           // sc1
        } else if (j < 192) {
            const int o = j - 176;
            const float inv = g1[o] * rsqrtf(rv1[o] + EPS);
            shb[j] = b1[o] - rm1[o] * inv;                   // sh1
        }
    }
}

// ---------------- Layer 1: voxel scatter, one thread per (voxel, oc-pair) ----------------
__global__ __launch_bounds__(256) void scatter_l1(
    const float* __restrict__ vf, const int* __restrict__ coors, int NV,
    const float* __restrict__ w1, const float* __restrict__ shb,
    unsigned short* __restrict__ y1, unsigned char* __restrict__ m1)
{
    __shared__ float ws[16 * 3 * 27];  // (oc, c, tap) -- pre-scaled by sc1[oc]
    for (int e = threadIdx.x; e < 16 * 3 * 27; e += 256)
        ws[e] = w1[e] * shb[160 + e / 81];
    __syncthreads();

    const int gid = blockIdx.x * 256 + threadIdx.x;
    const int i = gid >> 3;        // voxel
    const int oc2 = gid & 7;       // channel pair
    if (i < NV) {
        const int oc = oc2 * 2;

        const int b = coors[4 * i + 0];
        const int z = coors[4 * i + 1];
        const int y = coors[4 * i + 2];
        const int x = coors[4 * i + 3];
        const float f0 = vf[3 * i + 0];
        const float f1 = vf[3 * i + 1];
        const float f2 = vf[3 * i + 2];

        int ozv[2], kzv[2], nz = 0;
        int oyv[2], kyv[2], ny = 0;
        int oxv[2], kxv[2], nx = 0;
#pragma unroll
        for (int k = 0; k < 3; ++k) {
            int t = z + 1 - k;
            if (t >= 0 && !(t & 1)) { int o = t >> 1; if (o < 21) { ozv[nz] = o; kzv[nz] = k; ++nz; } }
        }
#pragma unroll
        for (int k = 0; k < 3; ++k) {
            int t = y + 1 - k;
            if (t >= 0 && !(t & 1)) { int o = t >> 1; if (o < 256) { oyv[ny] = o; kyv[ny] = k; ++ny; } }
        }
#pragma unroll
        for (int k = 0; k < 3; ++k) {
            int t = x + 1 - k;
            if (t >= 0 && !(t & 1)) { int o = t >> 1; if (o < 256) { oxv[nx] = o; kxv[nx] = k; ++nx; } }
        }

        for (int a = 0; a < nz; ++a)
            for (int bb = 0; bb < ny; ++bb)
                for (int c = 0; c < nx; ++c) {
                    const int oz = ozv[a], oy = oyv[bb], ox = oxv[c];
                    const int tap = (kzv[a] * 3 + kyv[bb]) * 3 + kxv[c];
                    const int sp = oz * 65536 + oy * 256 + ox;
                    if (oc2 == 0) m1[b * 1376256 + sp] = 1;
                    const float s0 = ws[oc * 81 + tap] * f0 + ws[oc * 81 + 27 + tap] * f1 +
                                     ws[oc * 81 + 54 + tap] * f2;
                    const float s1 = ws[(oc + 1) * 81 + tap] * f0 +
                                     ws[(oc + 1) * 81 + 27 + tap] * f1 +
                                     ws[(oc + 1) * 81 + 54 + tap] * f2;
                    const unsigned pk = f2bf(s0) | (f2bf(s1) << 16);
                    unsigned* addr = (unsigned*)(y1 + (size_t)(b * 1376256 + sp) * 16 +
                                                 oc2 * 2);
                    asm volatile("global_atomic_pk_add_bf16 %0, %1, off"
                                 : : "v"(addr), "v"(pk) : "memory");
                }
    }
    // CRITICAL (r25): drain inline-asm atomics before the wave can end.
    asm volatile("s_waitcnt vmcnt(0)" ::: "memory");
}

// ---------------- masks: m2 from m1 (27-OR); m3 via scatter-stores ----------------
__global__ __launch_bounds__(256) void masks_pass(
    const unsigned char* __restrict__ m1, float* __restrict__ m2,
    float* __restrict__ m3)
{
    const int idx = blockIdx.x * 256 + threadIdx.x;   // < 360448
    const int b = idx / 180224;
    const int r = idx - b * 180224;
    const int oz = r >> 14, r2 = r & 16383, oy = r2 >> 7, ox = r2 & 127;
    const int iz0 = 2 * oz - 1, iyb = 2 * oy - 1, ixb = 2 * ox - 1;
    unsigned msum = 0;
#pragma unroll
    for (int kz = 0; kz < 3; ++kz) {
        const int iz = iz0 + kz;
#pragma unroll
        for (int ky = 0; ky < 3; ++ky) {
            const int iy = iyb + ky;
#pragma unroll
            for (int kx = 0; kx < 3; ++kx) {
                const int ix = ixb + kx;
                if ((unsigned)iz < 21u && (unsigned)iy < 256u &&
                    (unsigned)ix < 256u)
                    msum |= m1[b * 1376256 + iz * 65536 + iy * 256 + ix];
            }
        }
    }
    m2[idx] = msum ? 1.f : 0.f;

    if (msum) {
        // parent m3 windows of this m2 px: z pad0 (o=(oz-k)/2), y/x pad1
        int ozv[2], nz = 0, oyv[2], ny = 0, oxv[2], nx = 0;
#pragma unroll
        for (int k = 0; k < 3; ++k) {
            int t = oz - k;
            if (t >= 0 && !(t & 1)) { int o = t >> 1; if (o < 5) ozv[nz++] = o; }
        }
#pragma unroll
        for (int k = 0; k < 3; ++k) {
            int t = oy + 1 - k;
            if (t >= 0 && !(t & 1)) { int o = t >> 1; if (o < 64) oyv[ny++] = o; }
        }
#pragma unroll
        for (int k = 0; k < 3; ++k) {
            int t = ox + 1 - k;
            if (t >= 0 && !(t & 1)) { int o = t >> 1; if (o < 64) oxv[nx++] = o; }
        }
        for (int a = 0; a < nz; ++a)
            for (int bb = 0; bb < ny; ++bb)
                for (int c = 0; c < nx; ++c)
                    m3[b * 20480 + ozv[a] * 4096 + oyv[bb] * 64 + oxv[c]] = 1.0f;
    }
}

// ---------------- Layer 2: LDS-staged implicit-GEMM MFMA 32x32x16 conv 16->32 ----------------
// Block = (plane, oy) x 128 output px; 4 waves each own a 32-px strip.
// Per kz: reg-stage 3 input rows (520 16B-units each): coalesced uint4 load +
// m1 byte, CONVERT (bn+relu+f16, gate) in regs, ds_write_b128 to the
// XOR-swizzled slot. Consume: 9 taps of pure ds_read_b128 + MFMA.
// Stage assignment l = it*256+tid: 520 even => unit half == tid&1 (constant).
__global__ __launch_bounds__(256) __attribute__((amdgpu_waves_per_eu(4, 8)))
void conv_l2(
    const unsigned char* __restrict__ y1c,  // ws base, byte-addressed
    const unsigned char* __restrict__ m1,
    const uint4* __restrict__ wB2,
    const float* __restrict__ m2, const float* __restrict__ shb,
    _Float16* __restrict__ h2h)
{
    __shared__ uint4 lds4[3 * 520];           // 3 rows x 8320 B
    unsigned char* lds = (unsigned char*)lds4;

    const int tid = threadIdx.x;
    const int lane = tid & 63;
    const int w = tid >> 6;
    const int m = lane & 31, h = lane >> 5;

    // oy-major order + XCD-chunked swizzle (2816 = 8 x 352, bijective)
    const int sbid = (blockIdx.x & 7) * 352 + (blockIdx.x >> 3);
    const int oy = sbid / 22;
    const int plane = sbid - oy * 22;          // b*11 + oz
    const int b = plane / 11, oz = plane - b * 11;

    const int ox0 = w * 32;
    const int iz0 = 2 * oz - 1, iyb = 2 * oy - 1;
    const int bbase = b * 1376256;
    const int qoff = h * 16;

    const int shalf = tid & 1;                 // staged cell-half (constant)

    // bn shifts for the staged half's channels shalf*8 .. +7
    float s1v[8];
    {
        const float4* sp = (const float4*)(shb + 176 + shalf * 8);
        const float4 a0 = sp[0], a1 = sp[1];
        s1v[0] = a0.x; s1v[1] = a0.y; s1v[2] = a0.z; s1v[3] = a0.w;
        s1v[4] = a1.x; s1v[5] = a1.y; s1v[6] = a1.z; s1v[7] = a1.w;
    }

    // reader LDS byte offsets per kx (logical->physical swizzle)
    int rdo[3];
#pragma unroll
    for (int kx = 0; kx < 3; ++kx) {
        const unsigned L = (unsigned)((2 * (ox0 + m) + kx) * 32 + qoff);
        rdo[kx] = (int)(L ^ (((L >> 7) & 7u) << 4));
    }

    // stage-unit geometry per it: l = it*256+tid over 3x520 units
    int st_row[7], st_ix[7], st_lws[7];
    bool st_ok[7];
#pragma unroll
    for (int it = 0; it < 7; ++it) {
        const int l = it * 256 + tid;
        st_ok[it] = l < 1560;
        const int row = l / 520;               // 0..2 when ok
        const int u = l - row * 520;           // u&1 == shalf
        const int lx = u >> 1;
        st_row[it] = row;
        st_ix[it] = lx - 1;
        const unsigned Ll = (unsigned)(lx * 32 + shalf * 16);
        st_lws[it] = row * 8320 + (int)(Ll ^ (((Ll >> 7) & 7u) << 4));
    }

    f32x16 acc;
#pragma unroll
    for (int r = 0; r < 16; ++r) acc[r] = 0.f;

    for (int kz = 0; kz < 3; ++kz) {
        const int iz = iz0 + kz;
        const bool izok = (unsigned)iz < 21u;
        const int zrow = bbase + iz * 65536;

        __syncthreads();    // prior consume done before LDS overwrite
        uint4 sd[7];
        unsigned char sm[7];
#pragma unroll
        for (int it = 0; it < 7; ++it) {
            if (st_ok[it]) {
                const int iy = iyb + st_row[it];
                const bool v = izok && (unsigned)iy < 256u &&
                               (unsigned)st_ix[it] < 256u;
                const int cell = zrow + iy * 256 + st_ix[it];
                sd[it] = *(const uint4*)(y1c +
                          (v ? (cell * 32 + shalf * 16) : (int)SLACK_Y1));
                sm[it] = m1[v ? cell : SLACK_BYTE];
            }
        }
#pragma unroll
        for (int it = 0; it < 7; ++it) {
            if (st_ok[it]) {
                const bool act = sm[it] != 0;
                unsigned od[4];
                const unsigned dvs[4] = {sd[it].x, sd[it].y, sd[it].z, sd[it].w};
#pragma unroll
                for (int jj = 0; jj < 4; ++jj) {
                    const unsigned dv = dvs[jj];
                    const float vlo = fmaxf(__uint_as_float(dv << 16) + s1v[2 * jj], 0.f);
                    const float vhi = fmaxf(__uint_as_float(dv & 0xFFFF0000u) + s1v[2 * jj + 1], 0.f);
                    const unsigned pk = __builtin_bit_cast(
                        unsigned, __builtin_amdgcn_cvt_pkrtz(vlo, vhi));
                    od[jj] = act ? pk : 0u;
                }
                const uint4 uc = {od[0], od[1], od[2], od[3]};
                *(uint4*)(lds + st_lws[it]) = uc;
            }
        }
        __syncthreads();

        // consume: pure ds_read_b128 + MFMA (no VALU between)
#pragma unroll
        for (int ky = 0; ky < 3; ++ky) {
#pragma unroll
            for (int kx = 0; kx < 3; ++kx) {
                const int tap = kz * 9 + ky * 3 + kx;
                const uint4 ua = *(const uint4*)(lds + ky * 8320 + rdo[kx]);
                const f16x8 af = __builtin_bit_cast(f16x8, ua);
                const f16x8 bf = __builtin_bit_cast(f16x8, wB2[tap * 64 + lane]);
                acc = __builtin_amdgcn_mfma_f32_32x32x16_f16(af, bf, acc, 0, 0, 0);
            }
        }
    }

    // epilogue: col=lane&31 (oc), row=(r&3)+8*(r>>2)+4*(lane>>5) (px)
    const int oc = lane & 31;
#pragma unroll
    for (int r = 0; r < 16; ++r) {
        const int row = (r & 3) + 8 * (r >> 2) + 4 * h;
        const int px = ox0 + row;
        const int spo = oz * 16384 + oy * 128 + px;
        const float mv = m2[b * 180224 + spo];
        const size_t cbase = (size_t)(b * 180224 + spo) * 32;
        h2h[cbase + oc] = (_Float16)(fmaxf(acc[r] + shb[oc], 0.f) * mv);
    }
}

// ---------------- Layer 3: implicit-GEMM MFMA conv 32->64 ----------------
__global__ __launch_bounds__(256) __attribute__((amdgpu_waves_per_eu(4, 8)))
void conv_l3(
    const unsigned char* __restrict__ h2h,  // f16 cells, byte-addressed
    const uint4* __restrict__ wB3,
    const float* __restrict__ m3, const float* __restrict__ shb,
    _Float16* __restrict__ h3h)
{
    const int tid = threadIdx.x;
    const int gw = blockIdx.x * 4 + (tid >> 6);     // 0..2559
    const int lane = tid & 63;
    const int m = lane & 15, q = lane >> 4;

    const int plane = gw >> 8;                      // b*5+oz
    const int rem = gw & 255;
    const int oy = rem >> 2;
    const int ox0 = (rem & 3) * 16;
    const int b = plane / 5, oz = plane % 5;
    const int iz0 = 2 * oz, iyb = 2 * oy - 1;       // z pad 0
    const int ixm = 2 * (ox0 + m) - 1;
    const int bbase = b * 180224;
    const int qoff = q * 16;                        // byte offset in 64B cell

    f32x4 acc[4];
#pragma unroll
    for (int t = 0; t < 4; ++t) acc[t] = (f32x4){0.f, 0.f, 0.f, 0.f};

    uint4 buf[9];
    bool  val[9];
#pragma unroll
    for (int t = 0; t < 9; ++t) {
        const int ky = (t / 3) % 3, kx = t % 3;
        const int iz = iz0 + t / 9, iy = iyb + ky, ix = ixm + kx;
        const bool v = (unsigned)iy < 128u && (unsigned)ix < 128u;
        const int cell = bbase + iz * 16384 + iy * 128 + ix;
        buf[t] = *(const uint4*)(h2h + (v ? (cell * 64 + qoff) : 0));
        val[t] = v;
    }

#pragma unroll
    for (int tap = 0; tap < 27; ++tap) {
        const int s = tap % 9;
        uint4 ua = buf[s];
        if (!val[s]) { ua.x = 0; ua.y = 0; ua.z = 0; ua.w = 0; }
        if (tap + 9 < 27) {
            const int t2 = tap + 9;
            const int kz = t2 / 9, ky = (t2 / 3) % 3, kx = t2 % 3;
            const int iz = iz0 + kz, iy = iyb + ky, ix = ixm + kx;
            const bool v = (unsigned)iy < 128u && (unsigned)ix < 128u;
            const int cell = bbase + iz * 16384 + iy * 128 + ix;
            buf[s] = *(const uint4*)(h2h + (v ? (cell * 64 + qoff) : 0));
            val[s] = v;
        }
        const f16x8 af = __builtin_bit_cast(f16x8, ua);
#pragma unroll
        for (int t = 0; t < 4; ++t) {
            const f16x8 bf = __builtin_bit_cast(f16x8, wB3[(tap * 4 + t) * 64 + lane]);
            acc[t] = __builtin_amdgcn_mfma_f32_16x16x32_f16(af, bf, acc[t], 0, 0, 0);
        }
    }

    const int n = lane & 15;
#pragma unroll
    for (int r = 0; r < 4; ++r) {
        const int px = ox0 + q * 4 + r;
        const int spo = oz * 4096 + oy * 64 + px;
        const float mv = m3[b * 20480 + spo];
        const size_t cb = (size_t)(b * 20480 + spo) * 64;
#pragma unroll
        for (int t = 0; t < 4; ++t) {
            const int oc = t * 16 + n;
            h3h[cb + oc] = (_Float16)(fmaxf(acc[t][r] + shb[32 + oc], 0.f) * mv);
        }
    }
}

// ---------------- Layer 4: implicit-GEMM MFMA conv 64->64, k(3,1,1) ----------------
__global__ __launch_bounds__(256) __attribute__((amdgpu_waves_per_eu(4, 8)))
void conv_l4(
    const unsigned char* __restrict__ h3h,  // f16 cells (128 B), byte-addressed
    const uint4* __restrict__ wB4,
    const float* __restrict__ m3, const float* __restrict__ shb,
    float* __restrict__ out)
{
    const int tid = threadIdx.x;
    const int gw = blockIdx.x * 4 + (tid >> 6);     // 0..1023
    const int lane = tid & 63;
    const int m = lane & 15, q = lane >> 4;

    const int b = gw >> 9, od = (gw >> 8) & 1;
    const int oy = (gw >> 2) & 63, ox0 = (gw & 3) * 16;
    const int cellbase = (b * 5 + 2 * od) * 4096 + oy * 64 + ox0 + m;

    f32x4 acc[4];
#pragma unroll
    for (int t = 0; t < 4; ++t) acc[t] = (f32x4){0.f, 0.f, 0.f, 0.f};

#pragma unroll
    for (int c = 0; c < 6; ++c) {
        const int dz = c >> 1;
        const size_t addr = (size_t)(cellbase + dz * 4096) * 128 +
                            (c & 1) * 64 + q * 16;
        const uint4 ua = *(const uint4*)(h3h + addr);
        const f16x8 af = __builtin_bit_cast(f16x8, ua);
#pragma unroll
        for (int t = 0; t < 4; ++t) {
            const f16x8 bf = __builtin_bit_cast(f16x8, wB4[(c * 4 + t) * 64 + lane]);
            acc[t] = __builtin_amdgcn_mfma_f32_16x16x32_f16(af, bf, acc[t], 0, 0, 0);
        }
    }

    const int n = lane & 15;
#pragma unroll
    for (int r = 0; r < 4; ++r) {
        const int px = ox0 + q * 4 + r;
        const int spo = oy * 64 + px;
        const float msum = m3[(b * 5 + 2 * od + 0) * 4096 + spo] +
                           m3[(b * 5 + 2 * od + 1) * 4096 + spo] +
                           m3[(b * 5 + 2 * od + 2) * 4096 + spo];
        const float mv = msum > 0.f ? 1.f : 0.f;
#pragma unroll
        for (int t = 0; t < 4; ++t) {
            const int oc = t * 16 + n;
            out[((b * 64 + oc) * 2 + od) * 4096 + spo] =
                fmaxf(acc[t][r] + shb[96 + oc], 0.f) * mv;
        }
    }
}

extern "C" void kernel_launch(void* const* d_in, const int* in_sizes, int n_in,
                              void* d_out, int out_size, void* d_ws, size_t ws_size,
                              hipStream_t stream)
{
    const float* vf    = (const float*)d_in[0];
    const int*   coors = (const int*)d_in[1];
    // d_in[2] = batch_size (==2, hardcoded in geometry)
    const float* w1 = (const float*)d_in[3];
    const float* g1 = (const float*)d_in[4];
    const float* b1 = (const float*)d_in[5];
    const float* rm1 = (const float*)d_in[6];
    const float* rv1 = (const float*)d_in[7];
    const float* w2 = (const float*)d_in[8];
    const float* g2 = (const float*)d_in[9];
    const float* b2 = (const float*)d_in[10];
    const float* rm2 = (const float*)d_in[11];
    const float* rv2 = (const float*)d_in[12];
    const float* w3 = (const float*)d_in[13];
    const float* g3 = (const float*)d_in[14];
    const float* b3 = (const float*)d_in[15];
    const float* rm3 = (const float*)d_in[16];
    const float* rv3 = (const float*)d_in[17];
    const float* w4 = (const float*)d_in[18];
    const float* g4 = (const float*)d_in[19];
    const float* b4 = (const float*)d_in[20];
    const float* rm4 = (const float*)d_in[21];
    const float* rv4 = (const float*)d_in[22];

    const int NV = in_sizes[0] / 3;

    float* ws = (float*)d_ws;
    float* y1  = ws;                   // 22,020,096 f-slots: bf16 (2,21,256,256,16)
    float* m1f = y1 + 22020096;        //  2,752,544 BYTES used (mask+slack+zero line)
    float* h2h = m1f + 2752512;        //  5,767,168 f-slots: f16 (2,11,128,128,32)
    float* m2  = h2h + 5767168;        //    360,448 f  (2,11,128,128)
    float* h3h = m2 + 360448;          //  1,310,720 f-slots: f16 (2,5,64,64,64)
    float* m3  = h3h + 1310720;        //     40,960 f  (2,5,64,64)
    float* wB2 = m3 + 40960;           //      7,168 f-slots (13824 f16 used)
    float* wB3 = wB2 + 7168;           //     27,648 f-slots (55296 f16)
    float* wB4 = wB3 + 27648;          //      6,144 f-slots (12288 f16)
    float* shb = wB4 + 6144;           //        192 f

    unsigned char* m1 = (unsigned char*)m1f;

    const int pzBlocks = (NV + 255) / 256;
    repack_prezero<<<1034 + pzBlocks, 256, 0, stream>>>(
        g1, b1, rm1, rv1,
        w2, g2, b2, rm2, rv2, w3, g3, b3, rm3, rv3,
        w4, g4, b4, rm4, rv4,
        (_Float16*)wB2, (_Float16*)wB3, (_Float16*)wB4, shb,
        coors, NV, (unsigned short*)y1, m1, m3);
    scatter_l1<<<(NV * 8 + 255) / 256, 256, 0, stream>>>(vf, coors, NV, w1, shb,
                                                         (unsigned short*)y1, m1);
    masks_pass<<<1408, 256, 0, stream>>>(m1, m2, m3);
    conv_l2<<<2816, 256, 0, stream>>>((const unsigned char*)d_ws, m1,
                                      (const uint4*)wB2, m2, shb, (_Float16*)h2h);
    conv_l3<<<640, 256, 0, stream>>>((const unsigned char*)h2h, (const uint4*)wB3,
                                     m3, shb, (_Float16*)h3h);
    conv_l4<<<256, 256, 0, stream>>>((const unsigned char*)h3h, (const uint4*)wB4,
                                     m3, shb, (float*)d_out);
}